// Round 1
// baseline (388.164 us; speedup 1.0000x reference)
//
#include <hip/hip_runtime.h>

// EMA Vector-Quantizer for MI355X (gfx950).
// N=16384 tokens, D=64, K=8192. Dominant cost: 16384x8192x64 fp32 GEMM for
// distance argmin (no fp32 MFMA on CDNA4 -> VALU).
// R17 (prev, 223us): w via wave-uniform s_load. SMEM is OOO -> lgkmcnt(0)
// drains kill pipelining; VALUBusy 65%, ~49% of the 109us VALU-issue floor.
// R18 (this): w staged per-wave via double-buffered global_load_lds (vmcnt
// is in-order and countable -> s_waitcnt vmcnt(2) keeps next chunk in
// flight under the whole chunk's compute). w_t relaid out chunk-contiguous
// [chunk][d][8] so one chunk = 2KB contiguous = 2 coalesced
// global_load_lds_dwordx4 per wave. Chunk = 8 codes so LDS fits 2 blocks/CU
// exactly: 64KB z_s + 4 waves x 2 x 2KB = 80KB/block, 160KB/CU.
// Hot loop per d: 1 ds_read_b128 (z, per-lane) + 2 uniform ds_read_b128
// (w broadcast, conflict-free) + 16 v_pk_fma_f32. No SMEM in the d-loop;
// the per-chunk wnorm s_load drain in the epilogue doubles as the WAR fence
// before the next stage overwrites the buffer read two chunks ago.
// Predicted: k_argmin ~135-155us, VALUBusy ~85-90%.

#define N_TOK 16384
#define K_EMB 8192
#define EMB_D 64
#define TN 256
#define GROUPS 8
#define KPG (K_EMB / GROUPS)   // 1024 codes per k-group; 256 per wave
#define CH 8                   // codes per staged chunk
#define NCH (256 / CH)         // 32 chunks per wave

typedef float v2f __attribute__((ext_vector_type(2)));

// d_out flat layout (float32), in reference return order:
// z_q (1048576) | loss | new_weight (524288) | new_cluster_size (8192) | new_embed_avg (524288)
#define OFF_LOSS 1048576
#define OFF_W    1048577
#define OFF_CS   1572865
#define OFF_EA   1581057

// scratch inside the z_q region of out (all < 1048576, overwritten by k_quant)
#define OUT_WT 0                        // w_c chunked: 8192*64 = 524288 floats
#define OUT_CD 524288                   // cand dist [GROUPS][N_TOK] = 131072
#define OUT_CI (524288 + 131072)        // cand idx  [GROUPS][N_TOK] = 131072

// ws float offsets
#define WS_NSUM  0
#define WS_LOSS  1
#define WS_WNORM 16
#define WS_IDX   (WS_WNORM + K_EMB)

// async global->LDS, 16B per lane (dest = wave-uniform base + lane*16)
__device__ __forceinline__ void gload16(const float* g, float* l) {
  __builtin_amdgcn_global_load_lds(
      (const __attribute__((address_space(1))) void*)g,
      (__attribute__((address_space(3))) void*)l, 16, 0, 0);
}

// ---------------------------------------------------------------------------
// K0: wnorm[k]; chunk-transpose weight -> w_c[k/8][d][k%8] (in out); zero accs.
__global__ void k_prep(const float* __restrict__ weight,
                       float* __restrict__ out, float* __restrict__ ws) {
  int gid = blockIdx.x * 256 + threadIdx.x;     // 0..131071
  int row = gid >> 4;                            // codebook row 0..8191
  int l16 = gid & 15;
  float4 w4 = *(const float4*)(weight + row * EMB_D + l16 * 4);
  float s = w4.x * w4.x + w4.y * w4.y + w4.z * w4.z + w4.w * w4.w;
  #pragma unroll
  for (int off = 8; off > 0; off >>= 1) s += __shfl_xor(s, off, 16);
  if (l16 == 0) ws[WS_WNORM + row] = s;

  // chunked-transposed copy: w_c[(row/8)*512 + d*8 + (row%8)], d = l16*4+c
  int cb = OUT_WT + (row >> 3) * (EMB_D * CH) + (row & 7);
  out[cb + (l16 * 4 + 0) * CH] = w4.x;
  out[cb + (l16 * 4 + 1) * CH] = w4.y;
  out[cb + (l16 * 4 + 2) * CH] = w4.z;
  out[cb + (l16 * 4 + 3) * CH] = w4.w;

  #pragma unroll
  for (int j = 0; j < 4; ++j) out[OFF_EA + gid * 4 + j] = 0.f;
  if (gid < K_EMB) out[OFF_CS + gid] = 0.f;
  if (gid == 0) { out[OFF_LOSS] = 0.f; ws[WS_NSUM] = 0.f; ws[WS_LOSS] = 0.f; }
}

// ---------------------------------------------------------------------------
// K1: distance argmin. Block = 256 threads = 4 waves sharing 256 tokens;
// wave w scans k-range [kbase + w*256, +256) in 32 chunks of 8 codes;
// lane owns 4 tokens. grid (64, 8) = 512 blocks = 2/CU (80KB LDS each).
// Per chunk: stage next 2KB via 2x global_load_lds_dwordx4 (wave-private
// double buffer, vmcnt(2) pipeline, no barriers); d-loop reads z per-lane +
// w broadcast from LDS; argmin epilogue reads wnorm (uniform s_load).
__global__ __launch_bounds__(256, 2) void k_argmin(
    const float* __restrict__ z, const float* __restrict__ wc,
    const float* __restrict__ wnorm, float* __restrict__ cd,
    int* __restrict__ ci) {
  __shared__ __align__(16) float z_s[EMB_D * TN];          // [d][n], 64 KB
  __shared__ __align__(16) float wbuf[4][2][CH * EMB_D];   // 4 waves x dbuf x 2KB
  const int t = threadIdx.x;
  const int n0 = blockIdx.x * TN;
  const int kbase = blockIdx.y * KPG;
  // z is (b, c, hw): z_flat[n][d] = z[b*65536 + d*1024 + hw], n = b*1024+hw.
  const float* zb = z + ((n0 >> 10) << 16) + (n0 & 1023);

  // 16384 floats = 4096 float4s; 256 threads -> 16 iterations.
  #pragma unroll
  for (int i = 0; i < 16; ++i) {
    int f4 = i * 256 + t;                 // 0..4095 float4s
    int d = f4 >> 6, c4 = (f4 & 63) * 4;
    *(float4*)(z_s + d * TN + c4) = *(const float4*)(zb + d * 1024 + c4);
  }
  __syncthreads();

  const int lane = t & 63;
  const int wid = __builtin_amdgcn_readfirstlane(t >> 6);  // 0..3, wave-uniform
  const int k0base = kbase + wid * 256;
  const float* zlane = z_s + lane * 4;    // this lane's 4 tokens

  // wave's 64KB contiguous w region: 32 chunks x 512 floats
  const float* wsrc = wc + (size_t)k0base * EMB_D;
  float* wb0 = &wbuf[wid][0][0];
  float* wb1 = &wbuf[wid][1][0];

  float bestd[4];
  int besti[4];
  #pragma unroll
  for (int i = 0; i < 4; ++i) { bestd[i] = 3.4e38f; besti[i] = 0; }

  // prologue: stage chunk 0 -> wb0 (2 x 1KB)
  gload16(wsrc + lane * 4,       wb0 + lane * 4);
  gload16(wsrc + 256 + lane * 4, wb0 + 256 + lane * 4);

  for (int kc = 0; kc < NCH; ++kc) {      // 32 chunks of 8 codes
    const int k0 = k0base + kc * CH;
    float* cbuf = (kc & 1) ? wb1 : wb0;

    if (kc + 1 < NCH) {
      float* nbuf = (kc & 1) ? wb0 : wb1;
      const float* nsrc = wsrc + (kc + 1) * (CH * EMB_D);
      gload16(nsrc + lane * 4,       nbuf + lane * 4);
      gload16(nsrc + 256 + lane * 4, nbuf + 256 + lane * 4);
      // current buffer's 2 loads are the oldest; let the 2 just-issued fly.
      asm volatile("s_waitcnt vmcnt(2)" ::: "memory");
    } else {
      asm volatile("s_waitcnt vmcnt(0)" ::: "memory");
    }

    v2f acc2[4][4];                       // [token][k-pair]
    #pragma unroll
    for (int n = 0; n < 4; ++n)
      #pragma unroll
      for (int p = 0; p < 4; ++p) acc2[n][p] = (v2f)(0.f);

    #pragma unroll 8
    for (int d = 0; d < EMB_D; ++d) {
      float4 zf = *(const float4*)(zlane + d * TN);        // per-lane b128
      const float4* wv = (const float4*)(cbuf + d * CH);   // uniform -> bcast
      float4 wa = wv[0], wq = wv[1];
      v2f wp[4] = {{wa.x, wa.y}, {wa.z, wa.w}, {wq.x, wq.y}, {wq.z, wq.w}};
      float zr[4] = {zf.x, zf.y, zf.z, zf.w};
      #pragma unroll
      for (int p = 0; p < 4; ++p) {
        #pragma unroll
        for (int n = 0; n < 4; ++n) {
          v2f zn = {zr[n], zr[n]};
          acc2[n][p] = __builtin_elementwise_fma(zn, wp[p], acc2[n][p]);
        }
      }
    }

    // dist = |w|^2 - 2*dot; k ascends (kc, kk) + strict <  == first-min.
    // wnorm s_load's lgkmcnt(0) drain here also fences the ds pipeline
    // before the next iteration's stage overwrites the old buffer.
    #pragma unroll
    for (int kk = 0; kk < CH; ++kk) {
      float wn = wnorm[k0 + kk];          // uniform -> scalar load
      #pragma unroll
      for (int n = 0; n < 4; ++n) {
        float dot = (kk & 1) ? acc2[n][kk >> 1].y : acc2[n][kk >> 1].x;
        float dist = fmaf(-2.f, dot, wn);
        if (dist < bestd[n]) { bestd[n] = dist; besti[n] = k0 + kk; }
      }
    }
  }

  // Block combine: stash per-wave bests in z_s (done reading it), then the
  // 256 threads reduce 4 waves in ascending-k order (waves cover ascending
  // k-ranges, so strict < keeps the smaller k on ties).
  __syncthreads();
  #pragma unroll
  for (int i = 0; i < 4; ++i) {
    int n = lane * 4 + i;
    z_s[wid * TN + n] = bestd[i];
    ((int*)z_s)[2048 + wid * TN + n] = besti[i];
  }
  __syncthreads();
  {
    int n = t;
    float bd = z_s[n];
    int bi = ((int*)z_s)[2048 + n];
    #pragma unroll
    for (int w = 1; w < 4; ++w) {
      float od = z_s[w * TN + n];
      int oi = ((int*)z_s)[2048 + w * TN + n];
      if (od < bd) { bd = od; bi = oi; }
    }
    cd[blockIdx.y * N_TOK + n0 + n] = bd;
    ci[blockIdx.y * N_TOK + n0 + n] = bi;
  }
}

// ---------------------------------------------------------------------------
// K2: reduce the GROUPS candidates per token; enc_sum atomics.
// Groups cover ascending k-ranges, so strict < keeps smallest index on tie.
__global__ void k_reduce(const float* __restrict__ cd, const int* __restrict__ ci,
                         int* __restrict__ idx, float* __restrict__ enc) {
  int n = blockIdx.x * 256 + threadIdx.x;
  float bd = cd[n]; int bi = ci[n];
  #pragma unroll
  for (int g = 1; g < GROUPS; ++g) {
    float od = cd[g * N_TOK + n];
    int oi = ci[g * N_TOK + n];
    if (od < bd) { bd = od; bi = oi; }
  }
  idx[n] = bi;
  atomicAdd(enc + bi, 1.0f);
}

// ---------------------------------------------------------------------------
// K3: z_q gather + straight-through output + loss partials + embed_sum atomics.
__global__ void k_quant(const float* __restrict__ z, const float* __restrict__ weight,
                        const int* __restrict__ idx, float* __restrict__ out,
                        float* __restrict__ embed_acc, float* __restrict__ ws) {
  int base = blockIdx.x * 1024 + threadIdx.x;
  float lsum = 0.f;
  #pragma unroll
  for (int i = 0; i < 4; ++i) {
    int e = base + i * 256;               // (b,c,hw) flat, same layout as z
    int c = (e >> 10) & 63;
    int n = ((e >> 16) << 10) | (e & 1023);
    int k = idx[n];
    float zv = z[e];
    float q = weight[k * EMB_D + c];
    out[e] = zv + (q - zv);               // straight-through value
    float d = q - zv;
    lsum += d * d;
    atomicAdd(embed_acc + k * EMB_D + c, zv);
  }
  #pragma unroll
  for (int off = 32; off > 0; off >>= 1) lsum += __shfl_xor(lsum, off, 64);
  __shared__ float red[4];
  int lane = threadIdx.x & 63, wv = threadIdx.x >> 6;
  if (lane == 0) red[wv] = lsum;
  __syncthreads();
  if (threadIdx.x == 0)
    atomicAdd(ws + WS_LOSS, red[0] + red[1] + red[2] + red[3]);
}

// ---------------------------------------------------------------------------
// K4: new_cluster_size (in place over enc_sum), n-sum, loss finalize.
__global__ void k_cluster(const float* __restrict__ cluster_in,
                          float* __restrict__ out, float* __restrict__ ws) {
  int k = blockIdx.x * 256 + threadIdx.x;
  float ncs = cluster_in[k] * 0.99f + 0.01f * out[OFF_CS + k];
  out[OFF_CS + k] = ncs;
  float s = ncs;
  #pragma unroll
  for (int off = 32; off > 0; off >>= 1) s += __shfl_xor(s, off, 64);
  __shared__ float red[4];
  int lane = threadIdx.x & 63, wv = threadIdx.x >> 6;
  if (lane == 0) red[wv] = s;
  __syncthreads();
  if (threadIdx.x == 0) atomicAdd(ws + WS_NSUM, red[0] + red[1] + red[2] + red[3]);
  if (blockIdx.x == 0 && threadIdx.x == 0)
    out[OFF_LOSS] = 0.25f * ws[WS_LOSS] * (1.0f / 1048576.0f);
}

// ---------------------------------------------------------------------------
// K5: smoothed cluster sizes -> new_weight; new_embed_avg (in place).
__global__ void k_final(const float* __restrict__ embed_avg,
                        float* __restrict__ out, const float* __restrict__ ws) {
  int e = blockIdx.x * 256 + threadIdx.x;   // < 524288
  int k = e >> 6;
  float ncs = out[OFF_CS + k];
  float nsum = ws[WS_NSUM];
  float sm = (ncs + 1e-5f) / (nsum + K_EMB * 1e-5f) * nsum;
  float ea = embed_avg[e] * 0.99f + 0.01f * out[OFF_EA + e];
  out[OFF_EA + e] = ea;
  out[OFF_W + e] = ea / sm;
}

// ---------------------------------------------------------------------------
extern "C" void kernel_launch(void* const* d_in, const int* in_sizes, int n_in,
                              void* d_out, int out_size, void* d_ws, size_t ws_size,
                              hipStream_t stream) {
  const float* z = (const float*)d_in[0];
  const float* weight = (const float*)d_in[1];
  const float* cluster = (const float*)d_in[2];
  const float* embed_avg = (const float*)d_in[3];
  float* out = (float*)d_out;
  float* ws = (float*)d_ws;
  float* wnorm = ws + WS_WNORM;
  int* idx = (int*)(ws + WS_IDX);
  float* wc = out + OUT_WT;               // scratch in z_q region
  float* cd = out + OUT_CD;
  int* ci = (int*)(out + OUT_CI);

  hipLaunchKernelGGL(k_prep, dim3(512), dim3(256), 0, stream, weight, out, ws);
  hipLaunchKernelGGL(k_argmin, dim3(N_TOK / TN, GROUPS), dim3(256), 0, stream,
                     z, wc, wnorm, cd, ci);
  hipLaunchKernelGGL(k_reduce, dim3(N_TOK / 256), dim3(256), 0, stream,
                     cd, ci, idx, out + OFF_CS);
  hipLaunchKernelGGL(k_quant, dim3(1024), dim3(256), 0, stream,
                     z, weight, idx, out, out + OFF_EA, ws);
  hipLaunchKernelGGL(k_cluster, dim3(K_EMB / 256), dim3(256), 0, stream,
                     cluster, out, ws);
  hipLaunchKernelGGL(k_final, dim3(524288 / 256), dim3(256), 0, stream,
                     embed_avg, out, ws);
}

// Round 2
// 361.418 us; speedup vs baseline: 1.0740x; 1.0740x over previous
//
#include <hip/hip_runtime.h>

// EMA Vector-Quantizer for MI355X (gfx950).
// N=16384 tokens, D=64, K=8192. Dominant cost: 16384x8192x64 fp32 GEMM for
// distance argmin (no fp32 MFMA on CDNA4 -> VALU). VALU floor 109us
// theoretical, ~167us at m07's measured 103TF achievable rate.
// R17 (223us): 256-thr blocks, 4 waves, w via wave-uniform s_load. VALUBusy
// 65%, Occupancy 19% (2 waves/SIMD).
// R18 (236us): w via global_load_lds dbuf; chunk 8 -> z ds_read traffic 2x;
// VALUBusy 67%. Lesson: mechanism of w-path is not the binder; TLP is.
// Both rounds idle ~35% because 2 waves/SIMD can't cover lgkm/SMEM latency.
// R19 (this): 512-thread blocks = 8 waves splitting the k-group 8 ways.
// Same 64KB z_s, NO wbuf (w back on the SMEM pipe, R17 hot loop verbatim:
// per d = 1 ds_read_b128 (z, 4 tokens) + 64B s_load (w->SGPRs) + 32
// v_pk_fma_f32). 2 blocks/CU x 8 waves = 16 waves/CU = 4 waves/SIMD ->
// double the latency cover. __launch_bounds__(512,4) caps VGPR at 128;
// demand ~88 -> no spill. Per-wave: 128 codes, 8 chunks of 16.
// Predicted: Occupancy ~37%, VALUBusy ~85%, k_argmin ~155-175us.

#define N_TOK 16384
#define K_EMB 8192
#define EMB_D 64
#define TN 256
#define GROUPS 8
#define KPG (K_EMB / GROUPS)   // 1024 codes per k-group; 128 per wave

typedef float v2f __attribute__((ext_vector_type(2)));

// d_out flat layout (float32), in reference return order:
// z_q (1048576) | loss | new_weight (524288) | new_cluster_size (8192) | new_embed_avg (524288)
#define OFF_LOSS 1048576
#define OFF_W    1048577
#define OFF_CS   1572865
#define OFF_EA   1581057

// scratch inside the z_q region of out (all < 1048576, overwritten by k_quant)
#define OUT_WT 0                        // w_t[d][k]: 64 x 8192 = 524288 floats
#define OUT_CD 524288                   // cand dist [GROUPS][N_TOK] = 131072
#define OUT_CI (524288 + 131072)        // cand idx  [GROUPS][N_TOK] = 131072

// ws float offsets
#define WS_NSUM  0
#define WS_LOSS  1
#define WS_WNORM 16
#define WS_IDX   (WS_WNORM + K_EMB)

// ---------------------------------------------------------------------------
// K0: wnorm[k]; transpose weight -> w_t[d][k] (in out); zero accumulators.
__global__ void k_prep(const float* __restrict__ weight,
                       float* __restrict__ out, float* __restrict__ ws) {
  int gid = blockIdx.x * 256 + threadIdx.x;     // 0..131071
  int row = gid >> 4;                            // codebook row 0..8191
  int l16 = gid & 15;
  float4 w4 = *(const float4*)(weight + row * EMB_D + l16 * 4);
  float s = w4.x * w4.x + w4.y * w4.y + w4.z * w4.z + w4.w * w4.w;
  #pragma unroll
  for (int off = 8; off > 0; off >>= 1) s += __shfl_xor(s, off, 16);
  if (l16 == 0) ws[WS_WNORM + row] = s;

  // transposed copy: w_t[d*8192 + row], d = l16*4+c
  out[OUT_WT + (l16 * 4 + 0) * K_EMB + row] = w4.x;
  out[OUT_WT + (l16 * 4 + 1) * K_EMB + row] = w4.y;
  out[OUT_WT + (l16 * 4 + 2) * K_EMB + row] = w4.z;
  out[OUT_WT + (l16 * 4 + 3) * K_EMB + row] = w4.w;

  #pragma unroll
  for (int j = 0; j < 4; ++j) out[OFF_EA + gid * 4 + j] = 0.f;
  if (gid < K_EMB) out[OFF_CS + gid] = 0.f;
  if (gid == 0) { out[OFF_LOSS] = 0.f; ws[WS_NSUM] = 0.f; ws[WS_LOSS] = 0.f; }
}

// ---------------------------------------------------------------------------
// K1: distance argmin. Block = 512 threads = 8 waves sharing 256 tokens;
// wave w scans k-range [kbase + w*128, +128) in 8 chunks of 16 codes;
// lane owns 4 tokens. grid (64, 8) = 512 blocks = 2/CU -> 16 waves/CU.
// Per d-iter: 1 ds_read_b128 (z, 4 tokens) + wave-uniform 64B s_load (w ->
// SGPRs) + 32 v_pk_fma_f32 (acc2[4][8] = 64 VGPRs; the SGPR pair is the one
// scalar operand each pk_fma allows).
__global__ __launch_bounds__(512, 4) void k_argmin(
    const float* __restrict__ z, const float* __restrict__ wt,
    const float* __restrict__ wnorm, float* __restrict__ cd,
    int* __restrict__ ci) {
  __shared__ __align__(16) float z_s[EMB_D * TN];  // [d][n], 64 KB
  const int t = threadIdx.x;
  const int n0 = blockIdx.x * TN;
  const int kbase = blockIdx.y * KPG;
  // z is (b, c, hw): z_flat[n][d] = z[b*65536 + d*1024 + hw], n = b*1024+hw.
  // TN=256 stays within one 1024-aligned b-slab (n0 is a multiple of 256).
  const float* zb = z + ((n0 >> 10) << 16) + (n0 & 1023);

  // 16384 floats = 4096 float4s; 512 threads -> 8 iterations.
  #pragma unroll
  for (int i = 0; i < 8; ++i) {
    int f4 = i * 512 + t;                 // 0..4095 float4s
    int d = f4 >> 6, c4 = (f4 & 63) * 4;
    *(float4*)(z_s + d * TN + c4) = *(const float4*)(zb + d * 1024 + c4);
  }
  __syncthreads();

  const int lane = t & 63;
  // wave id: provably wave-uniform -> w addresses become SGPR (s_load).
  const int wid = __builtin_amdgcn_readfirstlane(t >> 6);  // 0..7
  const int k0base = kbase + wid * 128;
  const float* zlane = z_s + lane * 4;    // this lane's 4 tokens

  float bestd[4];
  int besti[4];
  #pragma unroll
  for (int i = 0; i < 4; ++i) { bestd[i] = 3.4e38f; besti[i] = 0; }

  for (int kc = 0; kc < 8; ++kc) {        // 8 chunks of 16 codes
    const int k0 = k0base + kc * 16;
    const float* wrow = wt + k0;          // + d*K_EMB per d; uniform address

    v2f acc2[4][8];                       // [token][k-pair]
    #pragma unroll
    for (int n = 0; n < 4; ++n)
      #pragma unroll
      for (int p = 0; p < 8; ++p) acc2[n][p] = (v2f)(0.f);

    #pragma unroll 4
    for (int d = 0; d < EMB_D; ++d) {
      float4 zf = *(const float4*)(zlane + d * TN);   // ds_read_b128
      const v2f* wv = (const v2f*)(wrow + (size_t)d * K_EMB);  // s_load 64B
      float zr[4] = {zf.x, zf.y, zf.z, zf.w};
      #pragma unroll
      for (int p = 0; p < 8; ++p) {
        v2f w2 = wv[p];
        #pragma unroll
        for (int n = 0; n < 4; ++n) {
          v2f zn = {zr[n], zr[n]};
          acc2[n][p] = __builtin_elementwise_fma(zn, w2, acc2[n][p]);
        }
      }
    }

    // dist = |w|^2 - 2*dot; k ascends (kc, kk) + strict <  == first-min.
    #pragma unroll
    for (int kk = 0; kk < 16; ++kk) {
      float wn = wnorm[k0 + kk];          // uniform -> scalar load
      #pragma unroll
      for (int n = 0; n < 4; ++n) {
        float dot = (kk & 1) ? acc2[n][kk >> 1].y : acc2[n][kk >> 1].x;
        float dist = fmaf(-2.f, dot, wn);
        if (dist < bestd[n]) { bestd[n] = dist; besti[n] = k0 + kk; }
      }
    }
  }

  // Block combine: stash per-wave bests in z_s (done reading it), then
  // threads t<256 reduce 8 waves in ascending-k order (waves cover ascending
  // k-ranges, so strict < keeps the smaller k on ties).
  __syncthreads();
  #pragma unroll
  for (int i = 0; i < 4; ++i) {
    int n = lane * 4 + i;
    z_s[wid * TN + n] = bestd[i];                     // floats 0..2047
    ((int*)z_s)[2048 + wid * TN + n] = besti[i];      // ints 2048..4095
  }
  __syncthreads();
  if (t < TN) {
    int n = t;
    float bd = z_s[n];
    int bi = ((int*)z_s)[2048 + n];
    #pragma unroll
    for (int w = 1; w < 8; ++w) {
      float od = z_s[w * TN + n];
      int oi = ((int*)z_s)[2048 + w * TN + n];
      if (od < bd) { bd = od; bi = oi; }
    }
    cd[blockIdx.y * N_TOK + n0 + n] = bd;
    ci[blockIdx.y * N_TOK + n0 + n] = bi;
  }
}

// ---------------------------------------------------------------------------
// K2: reduce the GROUPS candidates per token; enc_sum atomics.
// Groups cover ascending k-ranges, so strict < keeps smallest index on tie.
__global__ void k_reduce(const float* __restrict__ cd, const int* __restrict__ ci,
                         int* __restrict__ idx, float* __restrict__ enc) {
  int n = blockIdx.x * 256 + threadIdx.x;
  float bd = cd[n]; int bi = ci[n];
  #pragma unroll
  for (int g = 1; g < GROUPS; ++g) {
    float od = cd[g * N_TOK + n];
    int oi = ci[g * N_TOK + n];
    if (od < bd) { bd = od; bi = oi; }
  }
  idx[n] = bi;
  atomicAdd(enc + bi, 1.0f);
}

// ---------------------------------------------------------------------------
// K3: z_q gather + straight-through output + loss partials + embed_sum atomics.
__global__ void k_quant(const float* __restrict__ z, const float* __restrict__ weight,
                        const int* __restrict__ idx, float* __restrict__ out,
                        float* __restrict__ embed_acc, float* __restrict__ ws) {
  int base = blockIdx.x * 1024 + threadIdx.x;
  float lsum = 0.f;
  #pragma unroll
  for (int i = 0; i < 4; ++i) {
    int e = base + i * 256;               // (b,c,hw) flat, same layout as z
    int c = (e >> 10) & 63;
    int n = ((e >> 16) << 10) | (e & 1023);
    int k = idx[n];
    float zv = z[e];
    float q = weight[k * EMB_D + c];
    out[e] = zv + (q - zv);               // straight-through value
    float d = q - zv;
    lsum += d * d;
    atomicAdd(embed_acc + k * EMB_D + c, zv);
  }
  #pragma unroll
  for (int off = 32; off > 0; off >>= 1) lsum += __shfl_xor(lsum, off, 64);
  __shared__ float red[4];
  int lane = threadIdx.x & 63, wv = threadIdx.x >> 6;
  if (lane == 0) red[wv] = lsum;
  __syncthreads();
  if (threadIdx.x == 0)
    atomicAdd(ws + WS_LOSS, red[0] + red[1] + red[2] + red[3]);
}

// ---------------------------------------------------------------------------
// K4: new_cluster_size (in place over enc_sum), n-sum, loss finalize.
__global__ void k_cluster(const float* __restrict__ cluster_in,
                          float* __restrict__ out, float* __restrict__ ws) {
  int k = blockIdx.x * 256 + threadIdx.x;
  float ncs = cluster_in[k] * 0.99f + 0.01f * out[OFF_CS + k];
  out[OFF_CS + k] = ncs;
  float s = ncs;
  #pragma unroll
  for (int off = 32; off > 0; off >>= 1) s += __shfl_xor(s, off, 64);
  __shared__ float red[4];
  int lane = threadIdx.x & 63, wv = threadIdx.x >> 6;
  if (lane == 0) red[wv] = s;
  __syncthreads();
  if (threadIdx.x == 0) atomicAdd(ws + WS_NSUM, red[0] + red[1] + red[2] + red[3]);
  if (blockIdx.x == 0 && threadIdx.x == 0)
    out[OFF_LOSS] = 0.25f * ws[WS_LOSS] * (1.0f / 1048576.0f);
}

// ---------------------------------------------------------------------------
// K5: smoothed cluster sizes -> new_weight; new_embed_avg (in place).
__global__ void k_final(const float* __restrict__ embed_avg,
                        float* __restrict__ out, const float* __restrict__ ws) {
  int e = blockIdx.x * 256 + threadIdx.x;   // < 524288
  int k = e >> 6;
  float ncs = out[OFF_CS + k];
  float nsum = ws[WS_NSUM];
  float sm = (ncs + 1e-5f) / (nsum + K_EMB * 1e-5f) * nsum;
  float ea = embed_avg[e] * 0.99f + 0.01f * out[OFF_EA + e];
  out[OFF_EA + e] = ea;
  out[OFF_W + e] = ea / sm;
}

// ---------------------------------------------------------------------------
extern "C" void kernel_launch(void* const* d_in, const int* in_sizes, int n_in,
                              void* d_out, int out_size, void* d_ws, size_t ws_size,
                              hipStream_t stream) {
  const float* z = (const float*)d_in[0];
  const float* weight = (const float*)d_in[1];
  const float* cluster = (const float*)d_in[2];
  const float* embed_avg = (const float*)d_in[3];
  float* out = (float*)d_out;
  float* ws = (float*)d_ws;
  float* wnorm = ws + WS_WNORM;
  int* idx = (int*)(ws + WS_IDX);
  float* wt = out + OUT_WT;               // scratch in z_q region
  float* cd = out + OUT_CD;
  int* ci = (int*)(out + OUT_CI);

  hipLaunchKernelGGL(k_prep, dim3(512), dim3(256), 0, stream, weight, out, ws);
  hipLaunchKernelGGL(k_argmin, dim3(N_TOK / TN, GROUPS), dim3(512), 0, stream,
                     z, wt, wnorm, cd, ci);
  hipLaunchKernelGGL(k_reduce, dim3(N_TOK / 256), dim3(256), 0, stream,
                     cd, ci, idx, out + OFF_CS);
  hipLaunchKernelGGL(k_quant, dim3(1024), dim3(256), 0, stream,
                     z, weight, idx, out, out + OFF_EA, ws);
  hipLaunchKernelGGL(k_cluster, dim3(K_EMB / 256), dim3(256), 0, stream,
                     cluster, out, ws);
  hipLaunchKernelGGL(k_final, dim3(524288 / 256), dim3(256), 0, stream,
                     embed_avg, out, ws);
}